// Round 11
// baseline (149.706 us; speedup 1.0000x reference)
//
#include <hip/hip_runtime.h>

typedef __attribute__((ext_vector_type(4))) short short4v;
typedef __attribute__((ext_vector_type(8))) short short8;
typedef __attribute__((ext_vector_type(4))) float f32x4;

#define NWIN 4096

__device__ __forceinline__ short f2bf(float f) {
    unsigned int u = __builtin_bit_cast(unsigned int, f);
    u += 0x7fffu + ((u >> 16) & 1u);
    return (short)(u >> 16);
}

// fast pack: round-half-up (differs from RNE only on exact ties)
__device__ __forceinline__ unsigned pack2h(float a, float b) {
    unsigned ua = __builtin_bit_cast(unsigned, a) + 0x8000u;
    unsigned ub = __builtin_bit_cast(unsigned, b) + 0x8000u;
    return (ua >> 16) | (ub & 0xffff0000u);
}

__device__ __forceinline__ short4v pk4h(float a, float b, float c, float d) {
    uint2 u;
    u.x = pack2h(a, b);
    u.y = pack2h(c, d);
    return __builtin_bit_cast(short4v, u);
}

#define LOG2E 1.4426950408889634f
#define QSCALE 0.17677669529663687f  // 32^-0.5

// ---- prep: transpose weights to bf16 (q-scale & log2e folded), permuted bias ----
__global__ void prep_kernel(const float* __restrict__ w_qkv,
                            const float* __restrict__ w_out,
                            const float* __restrict__ bias_table,
                            short* __restrict__ wqkvT,   // [384][128] bf16
                            short* __restrict__ woutT,   // [128][128] bf16
                            float* __restrict__ biasP)   // [4][4][64][16] f32, *log2e
{
    int id = blockIdx.x * 256 + threadIdx.x;
    if (id < 49152) {
        int j = id >> 7, k = id & 127;
        float v = w_qkv[k * 384 + j];
        if (j < 128) v *= (QSCALE * LOG2E);   // fold attention scale + log2e into Wq
        wqkvT[id] = f2bf(v);
    } else if (id < 65536) {
        int t = id - 49152;
        int j = t >> 7, k = t & 127;
        woutT[t] = f2bf(w_out[k * 128 + j]);
    } else if (id < 81920) {
        int t = id - 65536;
        // layout: [h][ib][ln][jb*4+r]; lane ln=(g<<4)|lo holds (i=16ib+lo, j=16jb+4g+r)
        int m  = t & 15;
        int ln = (t >> 4) & 63;
        int ib = (t >> 10) & 3;
        int h  = t >> 12;
        int lo = ln & 15, g = ln >> 4;
        int i = ib * 16 + lo;
        int j = (m >> 2) * 16 + g * 4 + (m & 3);
        int ri = i >> 3, ci = i & 7, rj = j >> 3, cj = j & 7;
        int idx = (ri - rj + 7) * 15 + (ci - cj + 7);
        biasP[t] = bias_table[idx * 4 + h] * LOG2E;
    }
}

// ---- fused, 2 windows per block: LN -> QKV -> attention -> out proj ----
__global__ __launch_bounds__(256, 2)
void attn_kernel(const float* __restrict__ x,
                 const float* __restrict__ gamma,
                 const float* __restrict__ beta,
                 const short* __restrict__ wqkvT,
                 const short* __restrict__ woutT,
                 const float* __restrict__ biasP,
                 float* __restrict__ out)
{
    // LDS map (64 KiB): XN[w] at w*16K; AO[w] at 32K + w*16K  (all swz layout)
    __shared__ __align__(16) char smem[65536];

    const int tid = threadIdx.x;
    const int h  = tid >> 6;
    const int ln = tid & 63;
    const int lo = ln & 15, g = ln >> 4;

    const float* xw0 = x + (size_t)(2 * blockIdx.x) * 8192;
    const float* xw1 = xw0 + 8192;

    // ---------------- LayerNorm both windows (16 lanes/row, 8 ch/lane) ----------------
    float4 va[2][4][2];
    #pragma unroll
    for (int p = 0; p < 4; ++p) {
        int t = h * 16 + p * 4 + g;
        const float4* xr0 = (const float4*)(xw0 + t * 128 + lo * 8);
        const float4* xr1 = (const float4*)(xw1 + t * 128 + lo * 8);
        va[0][p][0] = xr0[0]; va[0][p][1] = xr0[1];
        va[1][p][0] = xr1[0]; va[1][p][1] = xr1[1];
    }

    // prefetch kk=0 K-weight fragments (shared between windows)
    short8 pwk[2];
    #pragma unroll
    for (int cb = 0; cb < 2; ++cb)
        pwk[cb] = *(const short8*)(wqkvT + (128 + h * 32 + cb * 16 + lo) * 128 + g * 8);

    float4 ga0 = ((const float4*)gamma)[lo * 2], ga1 = ((const float4*)gamma)[lo * 2 + 1];
    float4 be0 = ((const float4*)beta)[lo * 2],  be1 = ((const float4*)beta)[lo * 2 + 1];

    #pragma unroll
    for (int w = 0; w < 2; ++w) {
        #pragma unroll
        for (int p = 0; p < 4; ++p) {
            int t = h * 16 + p * 4 + g;
            float4 v0 = va[w][p][0], v1 = va[w][p][1];
            float s  = v0.x + v0.y + v0.z + v0.w + v1.x + v1.y + v1.z + v1.w;
            float sq = v0.x*v0.x + v0.y*v0.y + v0.z*v0.z + v0.w*v0.w
                     + v1.x*v1.x + v1.y*v1.y + v1.z*v1.z + v1.w*v1.w;
            #pragma unroll
            for (int m = 1; m < 16; m <<= 1) {
                s  += __shfl_xor(s, m, 64);
                sq += __shfl_xor(sq, m, 64);
            }
            float mu  = s * (1.f / 128.f);
            float var = sq * (1.f / 128.f) - mu * mu;
            float rs  = rsqrtf(var + 1e-5f);
            float y0 = (v0.x - mu) * rs * ga0.x + be0.x;
            float y1 = (v0.y - mu) * rs * ga0.y + be0.y;
            float y2 = (v0.z - mu) * rs * ga0.z + be0.z;
            float y3 = (v0.w - mu) * rs * ga0.w + be0.w;
            float y4 = (v1.x - mu) * rs * ga1.x + be1.x;
            float y5 = (v1.y - mu) * rs * ga1.y + be1.y;
            float y6 = (v1.z - mu) * rs * ga1.z + be1.z;
            float y7 = (v1.w - mu) * rs * ga1.w + be1.w;
            uint4 pk;
            pk.x = pack2h(y0, y1); pk.y = pack2h(y2, y3);
            pk.z = pack2h(y4, y5); pk.w = pack2h(y6, y7);
            *(uint4*)(smem + w * 16384 + ((t * 256 + lo * 16) ^ ((t & 7) << 4))) = pk;
        }
    }
    __syncthreads();  // b1: XN ready

    const f32x4 z4 = {0.f, 0.f, 0.f, 0.f};

    // ---------------- QKV as 3 passes (K, Q, V), both windows interleaved ----------------
    short4v kA[2][2][4], qB[2][2][4], vA[2][2][4];   // [w][ck][..]

    // K pass (swapped: mfma(w, xn) -> D[c][t])
    {
        f32x4 acc[2][2][4];
        #pragma unroll
        for (int w = 0; w < 2; ++w)
            #pragma unroll
            for (int a = 0; a < 2; ++a)
                #pragma unroll
                for (int b = 0; b < 4; ++b) acc[w][a][b] = z4;
        #pragma unroll
        for (int kk = 0; kk < 4; ++kk) {
            short8 xa[2][4];
            #pragma unroll
            for (int w = 0; w < 2; ++w)
                #pragma unroll
                for (int tb = 0; tb < 4; ++tb) {
                    int t = tb * 16 + lo;
                    xa[w][tb] = *(const short8*)(smem + w * 16384 +
                        ((t * 256 + kk * 64 + g * 16) ^ ((t & 7) << 4)));
                }
            #pragma unroll
            for (int cb = 0; cb < 2; ++cb) {
                short8 wkf = (kk == 0) ? pwk[cb]
                    : *(const short8*)(wqkvT + (128 + h * 32 + cb * 16 + lo) * 128 + kk * 32 + g * 8);
                #pragma unroll
                for (int tb = 0; tb < 4; ++tb) {
                    acc[0][cb][tb] = __builtin_amdgcn_mfma_f32_16x16x32_bf16(wkf, xa[0][tb], acc[0][cb][tb], 0, 0, 0);
                    acc[1][cb][tb] = __builtin_amdgcn_mfma_f32_16x16x32_bf16(wkf, xa[1][tb], acc[1][cb][tb], 0, 0, 0);
                }
            }
        }
        #pragma unroll
        for (int w = 0; w < 2; ++w)
            #pragma unroll
            for (int ck = 0; ck < 2; ++ck)
                #pragma unroll
                for (int tb = 0; tb < 4; ++tb)
                    kA[w][ck][tb] = pk4h(acc[w][ck][tb][0], acc[w][ck][tb][1], acc[w][ck][tb][2], acc[w][ck][tb][3]);
    }
    // Q pass
    {
        f32x4 acc[2][2][4];
        #pragma unroll
        for (int w = 0; w < 2; ++w)
            #pragma unroll
            for (int a = 0; a < 2; ++a)
                #pragma unroll
                for (int b = 0; b < 4; ++b) acc[w][a][b] = z4;
        #pragma unroll
        for (int kk = 0; kk < 4; ++kk) {
            short8 xa[2][4];
            #pragma unroll
            for (int w = 0; w < 2; ++w)
                #pragma unroll
                for (int tb = 0; tb < 4; ++tb) {
                    int t = tb * 16 + lo;
                    xa[w][tb] = *(const short8*)(smem + w * 16384 +
                        ((t * 256 + kk * 64 + g * 16) ^ ((t & 7) << 4)));
                }
            #pragma unroll
            for (int cb = 0; cb < 2; ++cb) {
                short8 wqf = *(const short8*)(wqkvT + (h * 32 + cb * 16 + lo) * 128 + kk * 32 + g * 8);
                #pragma unroll
                for (int tb = 0; tb < 4; ++tb) {
                    acc[0][cb][tb] = __builtin_amdgcn_mfma_f32_16x16x32_bf16(wqf, xa[0][tb], acc[0][cb][tb], 0, 0, 0);
                    acc[1][cb][tb] = __builtin_amdgcn_mfma_f32_16x16x32_bf16(wqf, xa[1][tb], acc[1][cb][tb], 0, 0, 0);
                }
            }
        }
        #pragma unroll
        for (int w = 0; w < 2; ++w)
            #pragma unroll
            for (int ck = 0; ck < 2; ++ck)
                #pragma unroll
                for (int tb = 0; tb < 4; ++tb)
                    qB[w][ck][tb] = pk4h(acc[w][ck][tb][0], acc[w][ck][tb][1], acc[w][ck][tb][2], acc[w][ck][tb][3]);
    }
    // V pass (normal: mfma(xn, w) -> D[t][c]); acc[w][jk][cb] = V^T fragment directly
    {
        f32x4 acc[2][4][2];
        #pragma unroll
        for (int w = 0; w < 2; ++w)
            #pragma unroll
            for (int a = 0; a < 4; ++a)
                #pragma unroll
                for (int b = 0; b < 2; ++b) acc[w][a][b] = z4;
        #pragma unroll
        for (int kk = 0; kk < 4; ++kk) {
            short8 xa[2][4];
            #pragma unroll
            for (int w = 0; w < 2; ++w)
                #pragma unroll
                for (int tb = 0; tb < 4; ++tb) {
                    int t = tb * 16 + lo;
                    xa[w][tb] = *(const short8*)(smem + w * 16384 +
                        ((t * 256 + kk * 64 + g * 16) ^ ((t & 7) << 4)));
                }
            #pragma unroll
            for (int cb = 0; cb < 2; ++cb) {
                short8 wvf = *(const short8*)(wqkvT + (256 + h * 32 + cb * 16 + lo) * 128 + kk * 32 + g * 8);
                #pragma unroll
                for (int tb = 0; tb < 4; ++tb) {
                    acc[0][tb][cb] = __builtin_amdgcn_mfma_f32_16x16x32_bf16(xa[0][tb], wvf, acc[0][tb][cb], 0, 0, 0);
                    acc[1][tb][cb] = __builtin_amdgcn_mfma_f32_16x16x32_bf16(xa[1][tb], wvf, acc[1][tb][cb], 0, 0, 0);
                }
            }
        }
        #pragma unroll
        for (int w = 0; w < 2; ++w)
            #pragma unroll
            for (int cb = 0; cb < 2; ++cb)
                #pragma unroll
                for (int jk = 0; jk < 4; ++jk)
                    vA[w][cb][jk] = pk4h(acc[w][jk][cb][0], acc[w][jk][cb][1], acc[w][jk][cb][2], acc[w][jk][cb][3]);
    }

    // ---------------- per-ib: QK^T (bias C-in) -> exp2 -> PV -> AO write, both windows ----------------
    char* ao0 = smem + 32768;
    char* ao1 = smem + 49152;
    #pragma unroll
    for (int ib = 0; ib < 4; ++ib) {
        const f32x4* bp = (const f32x4*)(biasP + ((h * 4 + ib) * 64 + ln) * 16);
        f32x4 stA[4], stB[4];
        #pragma unroll
        for (int jb = 0; jb < 4; ++jb) { f32x4 b = bp[jb]; stA[jb] = b; stB[jb] = b; }

        __builtin_amdgcn_s_setprio(1);
        #pragma unroll
        for (int jb = 0; jb < 4; ++jb) {
            stA[jb] = __builtin_amdgcn_mfma_f32_16x16x16bf16_1k(kA[0][0][jb], qB[0][0][ib], stA[jb], 0, 0, 0);
            stB[jb] = __builtin_amdgcn_mfma_f32_16x16x16bf16_1k(kA[1][0][jb], qB[1][0][ib], stB[jb], 0, 0, 0);
            stA[jb] = __builtin_amdgcn_mfma_f32_16x16x16bf16_1k(kA[0][1][jb], qB[0][1][ib], stA[jb], 0, 0, 0);
            stB[jb] = __builtin_amdgcn_mfma_f32_16x16x16bf16_1k(kA[1][1][jb], qB[1][1][ib], stB[jb], 0, 0, 0);
        }
        __builtin_amdgcn_s_setprio(0);

        // softmax (no max-shift; fused exp2+sum+pack), both windows interleaved
        float sA = 0.f, sB = 0.f;
        short4v pA[4], pBv[4];
        #pragma unroll
        for (int jb = 0; jb < 4; ++jb) {
            float a0 = __builtin_exp2f(stA[jb][0]);
            float b0 = __builtin_exp2f(stB[jb][0]);
            float a1 = __builtin_exp2f(stA[jb][1]);
            float b1 = __builtin_exp2f(stB[jb][1]);
            float a2 = __builtin_exp2f(stA[jb][2]);
            float b2 = __builtin_exp2f(stB[jb][2]);
            float a3 = __builtin_exp2f(stA[jb][3]);
            float b3 = __builtin_exp2f(stB[jb][3]);
            sA += (a0 + a1) + (a2 + a3);
            sB += (b0 + b1) + (b2 + b3);
            pA[jb]  = pk4h(a0, a1, a2, a3);
            pBv[jb] = pk4h(b0, b1, b2, b3);
        }
        sA += __shfl_xor(sA, 16, 64);
        sB += __shfl_xor(sB, 16, 64);
        sA += __shfl_xor(sA, 32, 64);
        sB += __shfl_xor(sB, 32, 64);
        float invA = 1.f / sA, invB = 1.f / sB;

        // PV: O^T = V^T . P^T (registers only); ot transient per ib
        f32x4 otA[2] = {z4, z4}, otB[2] = {z4, z4};
        __builtin_amdgcn_s_setprio(1);
        #pragma unroll
        for (int jk = 0; jk < 4; ++jk)
            #pragma unroll
            for (int cb = 0; cb < 2; ++cb) {
                otA[cb] = __builtin_amdgcn_mfma_f32_16x16x16bf16_1k(vA[0][cb][jk], pA[jk],  otA[cb], 0, 0, 0);
                otB[cb] = __builtin_amdgcn_mfma_f32_16x16x16bf16_1k(vA[1][cb][jk], pBv[jk], otB[cb], 0, 0, 0);
            }
        __builtin_amdgcn_s_setprio(0);

        // AO writes for this ib (both windows)
        int i = ib * 16 + lo;
        int sw = (i & 7) << 4;
        #pragma unroll
        for (int cb = 0; cb < 2; ++cb) {
            uint2 wv0, wv1;
            wv0.x = pack2h(otA[cb][0] * invA, otA[cb][1] * invA);
            wv0.y = pack2h(otA[cb][2] * invA, otA[cb][3] * invA);
            wv1.x = pack2h(otB[cb][0] * invB, otB[cb][1] * invB);
            wv1.y = pack2h(otB[cb][2] * invB, otB[cb][3] * invB);
            int byte = (i * 256 + (h * 32 + cb * 16 + g * 4) * 2) ^ sw;
            *(uint2*)(ao0 + byte) = wv0;
            *(uint2*)(ao1 + byte) = wv1;
        }
    }

    // prefetch proj kk=0 weights before the barrier (shared)
    short8 wof0[2];
    #pragma unroll
    for (int cj = 0; cj < 2; ++cj)
        wof0[cj] = *(const short8*)(woutT + (h * 32 + cj * 16 + lo) * 128 + g * 8);

    __syncthreads();  // b2: AO ready

    // ---------------- out projection (swapped: out^T = Wout^T . AO^T, x32), both windows ----------------
    f32x4 ft[2][2][4];  // [w][cj][tb]
    #pragma unroll
    for (int w = 0; w < 2; ++w)
        #pragma unroll
        for (int a = 0; a < 2; ++a)
            #pragma unroll
            for (int b = 0; b < 4; ++b) ft[w][a][b] = z4;

    #pragma unroll
    for (int kk = 0; kk < 4; ++kk) {
        short8 ao[2][4];
        #pragma unroll
        for (int w = 0; w < 2; ++w)
            #pragma unroll
            for (int tb = 0; tb < 4; ++tb) {
                int t = tb * 16 + lo;
                ao[w][tb] = *(const short8*)((w ? ao1 : ao0) +
                    ((t * 256 + kk * 64 + g * 16) ^ ((t & 7) << 4)));
            }
        __builtin_amdgcn_s_setprio(1);
        #pragma unroll
        for (int cj = 0; cj < 2; ++cj) {
            short8 wof = (kk == 0) ? wof0[cj]
                : *(const short8*)(woutT + (h * 32 + cj * 16 + lo) * 128 + kk * 32 + g * 8);
            #pragma unroll
            for (int tb = 0; tb < 4; ++tb) {
                ft[0][cj][tb] = __builtin_amdgcn_mfma_f32_16x16x32_bf16(wof, ao[0][tb], ft[0][cj][tb], 0, 0, 0);
                ft[1][cj][tb] = __builtin_amdgcn_mfma_f32_16x16x32_bf16(wof, ao[1][tb], ft[1][cj][tb], 0, 0, 0);
            }
        }
        __builtin_amdgcn_s_setprio(0);
    }

    float* ow0 = out + (size_t)(2 * blockIdx.x) * 8192;
    float* ow1 = ow0 + 8192;
    #pragma unroll
    for (int cj = 0; cj < 2; ++cj)
        #pragma unroll
        for (int tb = 0; tb < 4; ++tb) {
            int t = tb * 16 + lo;
            *(f32x4*)(ow0 + t * 128 + h * 32 + cj * 16 + g * 4) = ft[0][cj][tb];
            *(f32x4*)(ow1 + t * 128 + h * 32 + cj * 16 + g * 4) = ft[1][cj][tb];
        }
}

extern "C" void kernel_launch(void* const* d_in, const int* in_sizes, int n_in,
                              void* d_out, int out_size, void* d_ws, size_t ws_size,
                              hipStream_t stream) {
    const float* x          = (const float*)d_in[0];
    const float* gamma      = (const float*)d_in[1];
    const float* beta       = (const float*)d_in[2];
    const float* w_qkv      = (const float*)d_in[3];
    const float* w_out      = (const float*)d_in[4];
    const float* bias_table = (const float*)d_in[5];

    short* wqkvT = (short*)d_ws;                    // 98304 B
    short* woutT = (short*)((char*)d_ws + 98304);   // 32768 B
    float* biasP = (float*)((char*)d_ws + 131072);  // 65536 B

    prep_kernel<<<320, 256, 0, stream>>>(w_qkv, w_out, bias_table, wqkvT, woutT, biasP);
    attn_kernel<<<NWIN / 2, 256, 0, stream>>>(x, gamma, beta, wqkvT, woutT, biasP, (float*)d_out);
}

// Round 13
// 148.486 us; speedup vs baseline: 1.0082x; 1.0082x over previous
//
#include <hip/hip_runtime.h>

typedef __attribute__((ext_vector_type(4))) short short4v;
typedef __attribute__((ext_vector_type(8))) short short8;
typedef __attribute__((ext_vector_type(4))) float f32x4;

#define NWIN 4096

__device__ __forceinline__ short f2bf(float f) {
    unsigned int u = __builtin_bit_cast(unsigned int, f);
    u += 0x7fffu + ((u >> 16) & 1u);
    return (short)(u >> 16);
}

// fast pack: round-half-up (differs from RNE only on exact ties)
__device__ __forceinline__ unsigned pack2h(float a, float b) {
    unsigned ua = __builtin_bit_cast(unsigned, a) + 0x8000u;
    unsigned ub = __builtin_bit_cast(unsigned, b) + 0x8000u;
    return (ua >> 16) | (ub & 0xffff0000u);
}

__device__ __forceinline__ short4v pk4h(float a, float b, float c, float d) {
    uint2 u;
    u.x = pack2h(a, b);
    u.y = pack2h(c, d);
    return __builtin_bit_cast(short4v, u);
}

#define LOG2E 1.4426950408889634f
#define QSCALE 0.17677669529663687f  // 32^-0.5

// ---- prep: transpose weights to bf16 (q-scale & log2e folded), permuted bias ----
__global__ void prep_kernel(const float* __restrict__ w_qkv,
                            const float* __restrict__ w_out,
                            const float* __restrict__ bias_table,
                            short* __restrict__ wqkvT,   // [384][128] bf16
                            short* __restrict__ woutT,   // [128][128] bf16
                            float* __restrict__ biasP)   // [4][4][64][16] f32, *log2e
{
    int id = blockIdx.x * 256 + threadIdx.x;
    if (id < 49152) {
        int j = id >> 7, k = id & 127;
        float v = w_qkv[k * 384 + j];
        if (j < 128) v *= (QSCALE * LOG2E);   // fold attention scale + log2e into Wq
        wqkvT[id] = f2bf(v);
    } else if (id < 65536) {
        int t = id - 49152;
        int j = t >> 7, k = t & 127;
        woutT[t] = f2bf(w_out[k * 128 + j]);
    } else if (id < 81920) {
        int t = id - 65536;
        // layout: [h][ib][ln][jb*4+r]; lane ln=(g<<4)|lo holds (i=16ib+lo, j=16jb+4g+r)
        int m  = t & 15;
        int ln = (t >> 4) & 63;
        int ib = (t >> 10) & 3;
        int h  = t >> 12;
        int lo = ln & 15, g = ln >> 4;
        int i = ib * 16 + lo;
        int j = (m >> 2) * 16 + g * 4 + (m & 3);
        int ri = i >> 3, ci = i & 7, rj = j >> 3, cj = j & 7;
        int idx = (ri - rj + 7) * 15 + (ci - cj + 7);
        biasP[t] = bias_table[idx * 4 + h] * LOG2E;
    }
}

// ---- fused, 2 windows per block: LN -> QKV -> attention -> out proj ----
__global__ __launch_bounds__(256, 2)
void attn_kernel(const float* __restrict__ x,
                 const float* __restrict__ gamma,
                 const float* __restrict__ beta,
                 const short* __restrict__ wqkvT,
                 const short* __restrict__ woutT,
                 const float* __restrict__ biasP,
                 float* __restrict__ out)
{
    // LDS map (64 KiB): XN[w] at w*16K; AO[w] at 32K + w*16K  (all swz layout)
    __shared__ __align__(16) char smem[65536];

    const int tid = threadIdx.x;
    const int h  = tid >> 6;
    const int ln = tid & 63;
    const int lo = ln & 15, g = ln >> 4;

    const float* xw0 = x + (size_t)(2 * blockIdx.x) * 8192;
    const float* xw1 = xw0 + 8192;

    // ---------------- LayerNorm both windows (16 lanes/row, 8 ch/lane) ----------------
    float4 va[2][4][2];
    #pragma unroll
    for (int p = 0; p < 4; ++p) {
        int t = h * 16 + p * 4 + g;
        const float4* xr0 = (const float4*)(xw0 + t * 128 + lo * 8);
        const float4* xr1 = (const float4*)(xw1 + t * 128 + lo * 8);
        va[0][p][0] = xr0[0]; va[0][p][1] = xr0[1];
        va[1][p][0] = xr1[0]; va[1][p][1] = xr1[1];
    }

    // prefetch kk=0 K-weight fragments (shared between windows)
    short8 pwk[2];
    #pragma unroll
    for (int cb = 0; cb < 2; ++cb)
        pwk[cb] = *(const short8*)(wqkvT + (128 + h * 32 + cb * 16 + lo) * 128 + g * 8);

    float4 ga0 = ((const float4*)gamma)[lo * 2], ga1 = ((const float4*)gamma)[lo * 2 + 1];
    float4 be0 = ((const float4*)beta)[lo * 2],  be1 = ((const float4*)beta)[lo * 2 + 1];

    #pragma unroll
    for (int w = 0; w < 2; ++w) {
        #pragma unroll
        for (int p = 0; p < 4; ++p) {
            int t = h * 16 + p * 4 + g;
            float4 v0 = va[w][p][0], v1 = va[w][p][1];
            float s  = v0.x + v0.y + v0.z + v0.w + v1.x + v1.y + v1.z + v1.w;
            float sq = v0.x*v0.x + v0.y*v0.y + v0.z*v0.z + v0.w*v0.w
                     + v1.x*v1.x + v1.y*v1.y + v1.z*v1.z + v1.w*v1.w;
            #pragma unroll
            for (int m = 1; m < 16; m <<= 1) {
                s  += __shfl_xor(s, m, 64);
                sq += __shfl_xor(sq, m, 64);
            }
            float mu  = s * (1.f / 128.f);
            float var = sq * (1.f / 128.f) - mu * mu;
            float rs  = rsqrtf(var + 1e-5f);
            float y0 = (v0.x - mu) * rs * ga0.x + be0.x;
            float y1 = (v0.y - mu) * rs * ga0.y + be0.y;
            float y2 = (v0.z - mu) * rs * ga0.z + be0.z;
            float y3 = (v0.w - mu) * rs * ga0.w + be0.w;
            float y4 = (v1.x - mu) * rs * ga1.x + be1.x;
            float y5 = (v1.y - mu) * rs * ga1.y + be1.y;
            float y6 = (v1.z - mu) * rs * ga1.z + be1.z;
            float y7 = (v1.w - mu) * rs * ga1.w + be1.w;
            uint4 pk;
            pk.x = pack2h(y0, y1); pk.y = pack2h(y2, y3);
            pk.z = pack2h(y4, y5); pk.w = pack2h(y6, y7);
            *(uint4*)(smem + w * 16384 + ((t * 256 + lo * 16) ^ ((t & 7) << 4))) = pk;
        }
    }
    __syncthreads();  // b1: XN ready

    const f32x4 z4 = {0.f, 0.f, 0.f, 0.f};

    // ---------------- QKV as 3 passes (K, Q, V), both windows interleaved ----------------
    short4v kA[2][2][4], qB[2][2][4], vA[2][2][4];   // [w][ck][..]

    // K pass (swapped: mfma(w, xn) -> D[c][t])
    {
        f32x4 acc[2][2][4];
        #pragma unroll
        for (int w = 0; w < 2; ++w)
            #pragma unroll
            for (int a = 0; a < 2; ++a)
                #pragma unroll
                for (int b = 0; b < 4; ++b) acc[w][a][b] = z4;
        #pragma unroll
        for (int kk = 0; kk < 4; ++kk) {
            short8 xa[2][4];
            #pragma unroll
            for (int w = 0; w < 2; ++w)
                #pragma unroll
                for (int tb = 0; tb < 4; ++tb) {
                    int t = tb * 16 + lo;
                    xa[w][tb] = *(const short8*)(smem + w * 16384 +
                        ((t * 256 + kk * 64 + g * 16) ^ ((t & 7) << 4)));
                }
            #pragma unroll
            for (int cb = 0; cb < 2; ++cb) {
                short8 wkf = (kk == 0) ? pwk[cb]
                    : *(const short8*)(wqkvT + (128 + h * 32 + cb * 16 + lo) * 128 + kk * 32 + g * 8);
                #pragma unroll
                for (int tb = 0; tb < 4; ++tb) {
                    acc[0][cb][tb] = __builtin_amdgcn_mfma_f32_16x16x32_bf16(wkf, xa[0][tb], acc[0][cb][tb], 0, 0, 0);
                    acc[1][cb][tb] = __builtin_amdgcn_mfma_f32_16x16x32_bf16(wkf, xa[1][tb], acc[1][cb][tb], 0, 0, 0);
                }
            }
        }
        #pragma unroll
        for (int w = 0; w < 2; ++w)
            #pragma unroll
            for (int ck = 0; ck < 2; ++ck)
                #pragma unroll
                for (int tb = 0; tb < 4; ++tb)
                    kA[w][ck][tb] = pk4h(acc[w][ck][tb][0], acc[w][ck][tb][1], acc[w][ck][tb][2], acc[w][ck][tb][3]);
    }
    // Q pass
    {
        f32x4 acc[2][2][4];
        #pragma unroll
        for (int w = 0; w < 2; ++w)
            #pragma unroll
            for (int a = 0; a < 2; ++a)
                #pragma unroll
                for (int b = 0; b < 4; ++b) acc[w][a][b] = z4;
        #pragma unroll
        for (int kk = 0; kk < 4; ++kk) {
            short8 xa[2][4];
            #pragma unroll
            for (int w = 0; w < 2; ++w)
                #pragma unroll
                for (int tb = 0; tb < 4; ++tb) {
                    int t = tb * 16 + lo;
                    xa[w][tb] = *(const short8*)(smem + w * 16384 +
                        ((t * 256 + kk * 64 + g * 16) ^ ((t & 7) << 4)));
                }
            #pragma unroll
            for (int cb = 0; cb < 2; ++cb) {
                short8 wqf = *(const short8*)(wqkvT + (h * 32 + cb * 16 + lo) * 128 + kk * 32 + g * 8);
                #pragma unroll
                for (int tb = 0; tb < 4; ++tb) {
                    acc[0][cb][tb] = __builtin_amdgcn_mfma_f32_16x16x32_bf16(wqf, xa[0][tb], acc[0][cb][tb], 0, 0, 0);
                    acc[1][cb][tb] = __builtin_amdgcn_mfma_f32_16x16x32_bf16(wqf, xa[1][tb], acc[1][cb][tb], 0, 0, 0);
                }
            }
        }
        #pragma unroll
        for (int w = 0; w < 2; ++w)
            #pragma unroll
            for (int ck = 0; ck < 2; ++ck)
                #pragma unroll
                for (int tb = 0; tb < 4; ++tb)
                    qB[w][ck][tb] = pk4h(acc[w][ck][tb][0], acc[w][ck][tb][1], acc[w][ck][tb][2], acc[w][ck][tb][3]);
    }
    // V pass (normal: mfma(xn, w) -> D[t][c]); acc[w][jk][cb] = V^T fragment directly
    {
        f32x4 acc[2][4][2];
        #pragma unroll
        for (int w = 0; w < 2; ++w)
            #pragma unroll
            for (int a = 0; a < 4; ++a)
                #pragma unroll
                for (int b = 0; b < 2; ++b) acc[w][a][b] = z4;
        #pragma unroll
        for (int kk = 0; kk < 4; ++kk) {
            short8 xa[2][4];
            #pragma unroll
            for (int w = 0; w < 2; ++w)
                #pragma unroll
                for (int tb = 0; tb < 4; ++tb) {
                    int t = tb * 16 + lo;
                    xa[w][tb] = *(const short8*)(smem + w * 16384 +
                        ((t * 256 + kk * 64 + g * 16) ^ ((t & 7) << 4)));
                }
            #pragma unroll
            for (int cb = 0; cb < 2; ++cb) {
                short8 wvf = *(const short8*)(wqkvT + (256 + h * 32 + cb * 16 + lo) * 128 + kk * 32 + g * 8);
                #pragma unroll
                for (int tb = 0; tb < 4; ++tb) {
                    acc[0][tb][cb] = __builtin_amdgcn_mfma_f32_16x16x32_bf16(xa[0][tb], wvf, acc[0][tb][cb], 0, 0, 0);
                    acc[1][tb][cb] = __builtin_amdgcn_mfma_f32_16x16x32_bf16(xa[1][tb], wvf, acc[1][tb][cb], 0, 0, 0);
                }
            }
        }
        #pragma unroll
        for (int w = 0; w < 2; ++w)
            #pragma unroll
            for (int cb = 0; cb < 2; ++cb)
                #pragma unroll
                for (int jk = 0; jk < 4; ++jk)
                    vA[w][cb][jk] = pk4h(acc[w][jk][cb][0], acc[w][jk][cb][1], acc[w][jk][cb][2], acc[w][jk][cb][3]);
    }

    // ---------------- per-ib: QK^T A+B -> smA -> PV A -> smB (covers PV A) -> AO A -> PV B -> AO B ----------------
    char* ao0 = smem + 32768;
    char* ao1 = smem + 49152;
    #pragma unroll
    for (int ib = 0; ib < 4; ++ib) {
        const f32x4* bp = (const f32x4*)(biasP + ((h * 4 + ib) * 64 + ln) * 16);
        f32x4 stA[4], stB[4];
        #pragma unroll
        for (int jb = 0; jb < 4; ++jb) { f32x4 b = bp[jb]; stA[jb] = b; stB[jb] = b; }

        __builtin_amdgcn_s_setprio(1);
        #pragma unroll
        for (int jb = 0; jb < 4; ++jb) {
            stA[jb] = __builtin_amdgcn_mfma_f32_16x16x16bf16_1k(kA[0][0][jb], qB[0][0][ib], stA[jb], 0, 0, 0);
            stB[jb] = __builtin_amdgcn_mfma_f32_16x16x16bf16_1k(kA[1][0][jb], qB[1][0][ib], stB[jb], 0, 0, 0);
            stA[jb] = __builtin_amdgcn_mfma_f32_16x16x16bf16_1k(kA[0][1][jb], qB[0][1][ib], stA[jb], 0, 0, 0);
            stB[jb] = __builtin_amdgcn_mfma_f32_16x16x16bf16_1k(kA[1][1][jb], qB[1][1][ib], stB[jb], 0, 0, 0);
        }
        __builtin_amdgcn_s_setprio(0);

        int i = ib * 16 + lo;
        int byte0 = (i * 256 + (h * 32 + g * 4) * 2) ^ ((i & 7) << 4);
        int byte1 = byte0 ^ 32;  // cb=1: pre-XOR +32; X bit5==0 so (X+32)^sw == byte0^32

        // ---- window A softmax (4 temps at a time) ----
        float sA = 0.f;
        short4v pA[4];
        #pragma unroll
        for (int jb = 0; jb < 4; ++jb) {
            float e0 = __builtin_exp2f(stA[jb][0]);
            float e1 = __builtin_exp2f(stA[jb][1]);
            float e2 = __builtin_exp2f(stA[jb][2]);
            float e3 = __builtin_exp2f(stA[jb][3]);
            sA += (e0 + e1) + (e2 + e3);
            pA[jb] = pk4h(e0, e1, e2, e3);
        }
        sA += __shfl_xor(sA, 16, 64);
        sA += __shfl_xor(sA, 32, 64);
        float invA = 1.f / sA;

        // ---- PV A (issue; latency covered by softmax B below) ----
        f32x4 otA[2] = {z4, z4};
        __builtin_amdgcn_s_setprio(1);
        #pragma unroll
        for (int jk = 0; jk < 4; ++jk)
            #pragma unroll
            for (int cb = 0; cb < 2; ++cb)
                otA[cb] = __builtin_amdgcn_mfma_f32_16x16x16bf16_1k(vA[0][cb][jk], pA[jk], otA[cb], 0, 0, 0);
        __builtin_amdgcn_s_setprio(0);

        // ---- window B softmax (pA dead; overlaps PV A) ----
        float sB = 0.f;
        short4v pBv[4];
        #pragma unroll
        for (int jb = 0; jb < 4; ++jb) {
            float e0 = __builtin_exp2f(stB[jb][0]);
            float e1 = __builtin_exp2f(stB[jb][1]);
            float e2 = __builtin_exp2f(stB[jb][2]);
            float e3 = __builtin_exp2f(stB[jb][3]);
            sB += (e0 + e1) + (e2 + e3);
            pBv[jb] = pk4h(e0, e1, e2, e3);
        }
        sB += __shfl_xor(sB, 16, 64);
        sB += __shfl_xor(sB, 32, 64);
        float invB = 1.f / sB;

        // ---- AO write A ----
        {
            uint2 wv;
            wv.x = pack2h(otA[0][0] * invA, otA[0][1] * invA);
            wv.y = pack2h(otA[0][2] * invA, otA[0][3] * invA);
            *(uint2*)(ao0 + byte0) = wv;
            wv.x = pack2h(otA[1][0] * invA, otA[1][1] * invA);
            wv.y = pack2h(otA[1][2] * invA, otA[1][3] * invA);
            *(uint2*)(ao0 + byte1) = wv;
        }

        // ---- PV B ----
        f32x4 otB[2] = {z4, z4};
        __builtin_amdgcn_s_setprio(1);
        #pragma unroll
        for (int jk = 0; jk < 4; ++jk)
            #pragma unroll
            for (int cb = 0; cb < 2; ++cb)
                otB[cb] = __builtin_amdgcn_mfma_f32_16x16x16bf16_1k(vA[1][cb][jk], pBv[jk], otB[cb], 0, 0, 0);
        __builtin_amdgcn_s_setprio(0);

        // ---- AO write B ----
        {
            uint2 wv;
            wv.x = pack2h(otB[0][0] * invB, otB[0][1] * invB);
            wv.y = pack2h(otB[0][2] * invB, otB[0][3] * invB);
            *(uint2*)(ao1 + byte0) = wv;
            wv.x = pack2h(otB[1][0] * invB, otB[1][1] * invB);
            wv.y = pack2h(otB[1][2] * invB, otB[1][3] * invB);
            *(uint2*)(ao1 + byte1) = wv;
        }
    }

    // prefetch proj kk=0 weights before the barrier (shared)
    short8 wof0[2];
    #pragma unroll
    for (int cj = 0; cj < 2; ++cj)
        wof0[cj] = *(const short8*)(woutT + (h * 32 + cj * 16 + lo) * 128 + g * 8);

    __syncthreads();  // b2: AO ready

    // ---------------- out projection (swapped: out^T = Wout^T . AO^T, x32), both windows ----------------
    f32x4 ft[2][2][4];  // [w][cj][tb]
    #pragma unroll
    for (int w = 0; w < 2; ++w)
        #pragma unroll
        for (int a = 0; a < 2; ++a)
            #pragma unroll
            for (int b = 0; b < 4; ++b) ft[w][a][b] = z4;

    #pragma unroll
    for (int kk = 0; kk < 4; ++kk) {
        short8 ao[2][4];
        #pragma unroll
        for (int w = 0; w < 2; ++w)
            #pragma unroll
            for (int tb = 0; tb < 4; ++tb) {
                int t = tb * 16 + lo;
                ao[w][tb] = *(const short8*)((w ? ao1 : ao0) +
                    ((t * 256 + kk * 64 + g * 16) ^ ((t & 7) << 4)));
            }
        __builtin_amdgcn_s_setprio(1);
        #pragma unroll
        for (int cj = 0; cj < 2; ++cj) {
            short8 wof = (kk == 0) ? wof0[cj]
                : *(const short8*)(woutT + (h * 32 + cj * 16 + lo) * 128 + kk * 32 + g * 8);
            #pragma unroll
            for (int tb = 0; tb < 4; ++tb) {
                ft[0][cj][tb] = __builtin_amdgcn_mfma_f32_16x16x32_bf16(wof, ao[0][tb], ft[0][cj][tb], 0, 0, 0);
                ft[1][cj][tb] = __builtin_amdgcn_mfma_f32_16x16x32_bf16(wof, ao[1][tb], ft[1][cj][tb], 0, 0, 0);
            }
        }
        __builtin_amdgcn_s_setprio(0);
    }

    float* ow0 = out + (size_t)(2 * blockIdx.x) * 8192;
    float* ow1 = ow0 + 8192;
    #pragma unroll
    for (int cj = 0; cj < 2; ++cj)
        #pragma unroll
        for (int tb = 0; tb < 4; ++tb) {
            int t = tb * 16 + lo;
            *(f32x4*)(ow0 + t * 128 + h * 32 + cj * 16 + g * 4) = ft[0][cj][tb];
            *(f32x4*)(ow1 + t * 128 + h * 32 + cj * 16 + g * 4) = ft[1][cj][tb];
        }
}

extern "C" void kernel_launch(void* const* d_in, const int* in_sizes, int n_in,
                              void* d_out, int out_size, void* d_ws, size_t ws_size,
                              hipStream_t stream) {
    const float* x          = (const float*)d_in[0];
    const float* gamma      = (const float*)d_in[1];
    const float* beta       = (const float*)d_in[2];
    const float* w_qkv      = (const float*)d_in[3];
    const float* w_out      = (const float*)d_in[4];
    const float* bias_table = (const float*)d_in[5];

    short* wqkvT = (short*)d_ws;                    // 98304 B
    short* woutT = (short*)((char*)d_ws + 98304);   // 32768 B
    float* biasP = (float*)((char*)d_ws + 131072);  // 65536 B

    prep_kernel<<<320, 256, 0, stream>>>(w_qkv, w_out, bias_table, wqkvT, woutT, biasP);
    attn_kernel<<<NWIN / 2, 256, 0, stream>>>(x, gamma, beta, wqkvT, woutT, biasP, (float*)d_out);
}